// Round 12
// baseline (876.745 us; speedup 1.0000x reference)
//
#include <hip/hip_runtime.h>
#include <hip/hip_bf16.h>

#define F_IN 512
#define NC 64      // HID == N_CLS == 64
#define NITER 10
#define BM 128     // MLP tile rows (391 blocks)

typedef float fvec4 __attribute__((ext_vector_type(4)));  // clang-native vec

// prop buffers use CHUNKED layout: pb[c][node][16], c = feature/16, so each
// chunk region is (N+1)*16 floats = 3.2MB -> fits a 4MB per-XCD L2.

// ---------------------------------------------------------------------------
// Fused tiled MLP: out[r,:] = relu(x[r,:] @ W1 + b1) @ W2 + b2   (all fp32)
// R10 structure (82us, SQ_LDS_BANK_CONFLICT=0, no reg spill); output store
// goes to the chunked prop layout. Accumulation order (k ascending) identical
// to all prior rounds -> bitwise identical MLP output.
__global__ __launch_bounds__(256) void mlp_kernel(
    const float* __restrict__ x, const float* __restrict__ W1,
    const float* __restrict__ b1, const float* __restrict__ W2,
    const float* __restrict__ b2, float* __restrict__ out, int N) {
  __shared__ float xs[BM * NC];    // 32KB x k-tile / later h
  __shared__ float ws[NC * NC];    // 16KB W1 k-tile / later W2
  const int tid  = threadIdx.x;
  const int brow = blockIdx.x * BM;
  const int rg = tid >> 4;         // 0..15 row-group (8 rows each)
  const int cg = tid & 15;         // 0..15 col-group (4 cols each)
  const int r0 = rg * 8;
  const int c0 = cg * 4;
  const int keyr = rg & 7;

  float acc[8][4];
#pragma unroll
  for (int j = 0; j < 4; ++j) {
    float bv = b1[c0 + j];
#pragma unroll
    for (int i = 0; i < 8; ++i) acc[i][j] = bv;
  }

  for (int kt = 0; kt < F_IN; kt += 64) {
#pragma unroll
    for (int q = 0; q < 8; ++q) {
      int c = q * 256 + tid;           // 2048 chunks
      int row = c >> 4, kc = c & 15;
      int gr = brow + row; if (gr >= N) gr = N - 1;
      float4 v = *reinterpret_cast<const float4*>(&x[(size_t)gr * F_IN + kt + kc * 4]);
      *reinterpret_cast<float4*>(&xs[row * NC + ((kc ^ ((row >> 3) & 7)) << 2)]) = v;
    }
#pragma unroll
    for (int q = 0; q < 4; ++q) {
      int c = q * 256 + tid;           // 1024 chunks
      *reinterpret_cast<float4*>(&ws[c * 4]) =
          *reinterpret_cast<const float4*>(&W1[(size_t)kt * NC + c * 4]);
    }
    __syncthreads();
#pragma unroll 4
    for (int kc = 0; kc < 16; ++kc) {
      float4 xq[8];
#pragma unroll
      for (int i = 0; i < 8; ++i)
        xq[i] = *reinterpret_cast<const float4*>(&xs[(r0 + i) * NC + ((kc ^ keyr) << 2)]);
#pragma unroll
      for (int m = 0; m < 4; ++m) {
        float4 wv = *reinterpret_cast<const float4*>(&ws[(kc * 4 + m) * NC + c0]);
        float wr[4] = {wv.x, wv.y, wv.z, wv.w};
#pragma unroll
        for (int i = 0; i < 8; ++i) {
          float xm = reinterpret_cast<const float*>(&xq[i])[m];
#pragma unroll
          for (int j = 0; j < 4; ++j) acc[i][j] = fmaf(xm, wr[j], acc[i][j]);
        }
      }
    }
    __syncthreads();
  }

  // ReLU; h -> xs (same swizzled layout)
#pragma unroll
  for (int i = 0; i < 8; ++i) {
    float4 hv = make_float4(fmaxf(acc[i][0], 0.f), fmaxf(acc[i][1], 0.f),
                            fmaxf(acc[i][2], 0.f), fmaxf(acc[i][3], 0.f));
    *reinterpret_cast<float4*>(&xs[(r0 + i) * NC + ((cg ^ keyr) << 2)]) = hv;
  }
#pragma unroll
  for (int q = 0; q < 4; ++q) {
    int c = q * 256 + tid;
    *reinterpret_cast<float4*>(&ws[c * 4]) =
        *reinterpret_cast<const float4*>(&W2[c * 4]);
  }
  float acc2[8][4];
#pragma unroll
  for (int j = 0; j < 4; ++j) {
    float bv = b2[c0 + j];
#pragma unroll
    for (int i = 0; i < 8; ++i) acc2[i][j] = bv;
  }
  __syncthreads();
#pragma unroll 4
  for (int kc = 0; kc < 16; ++kc) {
    float4 xq[8];
#pragma unroll
    for (int i = 0; i < 8; ++i)
      xq[i] = *reinterpret_cast<const float4*>(&xs[(r0 + i) * NC + ((kc ^ keyr) << 2)]);
#pragma unroll
    for (int m = 0; m < 4; ++m) {
      float4 wv = *reinterpret_cast<const float4*>(&ws[(kc * 4 + m) * NC + c0]);
      float wr[4] = {wv.x, wv.y, wv.z, wv.w};
#pragma unroll
      for (int i = 0; i < 8; ++i) {
        float xm = reinterpret_cast<const float*>(&xq[i])[m];
#pragma unroll
        for (int j = 0; j < 4; ++j) acc2[i][j] = fmaf(xm, wr[j], acc2[i][j]);
      }
    }
  }
  // chunked store: cols c0..c0+3 live in chunk cg>>2 at feature (c0 & 15)
#pragma unroll
  for (int i = 0; i < 8; ++i) {
    int gr = brow + r0 + i;
    if (gr < N) {
      fvec4 o = {acc2[i][0], acc2[i][1], acc2[i][2], acc2[i][3]};
      size_t dsto = (size_t)(cg >> 2) * (N + 1) * 16 + (size_t)gr * 16 + (c0 & 15);
      __builtin_nontemporal_store(o, reinterpret_cast<fvec4*>(&out[dsto]));
    }
  }
}

// ---------------------------------------------------------------------------
// Degree histograms (int atomics -> deterministic counts).
__global__ __launch_bounds__(256) void hist_kernel(
    const int* __restrict__ ei, int* __restrict__ deg_i,
    int* __restrict__ indeg, int E) {
  int e = blockIdx.x * blockDim.x + threadIdx.x;
  if (e < E) {
    atomicAdd(&deg_i[ei[e]], 1);       // row = edge_index[0]
    atomicAdd(&indeg[ei[E + e]], 1);   // col = edge_index[1]
  }
}

// ---------------------------------------------------------------------------
// Exclusive scan of PADDED indeg (multiple of 8) -> rowptr; also dis[].
__device__ __forceinline__ int pad8(int v) { return (v + 7) & ~7; }

__global__ __launch_bounds__(256) void scan_sum_kernel(
    const int* __restrict__ indeg, int* __restrict__ bsum,
    const int* __restrict__ deg_i, float* __restrict__ dis, int N) {
  __shared__ int sm[256];
  int tid = threadIdx.x;
  int i = blockIdx.x * 256 + tid;
  sm[tid] = (i < N) ? pad8(indeg[i]) : 0;
  if (i < N) dis[i] = 1.0f / sqrtf((float)(deg_i[i] + 1));  // +1 self-loop
  if (i == N) dis[N] = 0.0f;   // sentinel: pad edges have zero weight
  __syncthreads();
  for (int s = 128; s > 0; s >>= 1) {
    if (tid < s) sm[tid] += sm[tid + s];
    __syncthreads();
  }
  if (tid == 0) bsum[blockIdx.x] = sm[0];
}

__global__ __launch_bounds__(256) void scan_bsum_kernel(int* __restrict__ bsum, int nb) {
  __shared__ int sm[256];
  int tid = threadIdx.x;
  int v = (tid < nb) ? bsum[tid] : 0;
  sm[tid] = v;
  __syncthreads();
  for (int s = 1; s < 256; s <<= 1) {
    int t = (tid >= s) ? sm[tid - s] : 0;
    __syncthreads();
    sm[tid] += t;
    __syncthreads();
  }
  if (tid < nb) bsum[tid] = sm[tid] - v;  // exclusive
}

__global__ __launch_bounds__(256) void scan_final_kernel(
    const int* __restrict__ indeg, const int* __restrict__ bsum,
    int* __restrict__ rowptr, int N) {
  __shared__ int sm[256];
  int tid = threadIdx.x;
  int i = blockIdx.x * 256 + tid;
  int v = (i < N) ? pad8(indeg[i]) : 0;
  sm[tid] = v;
  __syncthreads();
  for (int s = 1; s < 256; s <<= 1) {
    int t = (tid >= s) ? sm[tid - s] : 0;
    __syncthreads();
    sm[tid] += t;
    __syncthreads();
  }
  if (i < N) {
    rowptr[i] = bsum[blockIdx.x] + sm[tid] - v;
    if (i == N - 1) rowptr[N] = bsum[blockIdx.x] + sm[tid];  // padded total
  }
}

// ---------------------------------------------------------------------------
// Build destination-CSR: csr[pos] = src only (4B); weight recomputed later.
__global__ __launch_bounds__(256) void scatter_kernel(
    const int* __restrict__ ei, const int* __restrict__ rowptr,
    int* __restrict__ cursor, int* __restrict__ csr, int E) {
  int e = blockIdx.x * blockDim.x + threadIdx.x;
  if (e < E) {
    int s = ei[e];
    int c = ei[E + e];
    int pos = rowptr[c] + atomicAdd(&cursor[c], 1);
    csr[pos] = s;
  }
}

// Fill pad slots with sentinel src=N (dis[N]=0); zero prop row N (all chunks).
__global__ __launch_bounds__(256) void pad_fill_kernel(
    const int* __restrict__ rowptr, const int* __restrict__ indeg,
    int* __restrict__ csr, float* __restrict__ propA,
    float* __restrict__ propB, int N) {
  int i = blockIdx.x * blockDim.x + threadIdx.x;
  if (blockIdx.x == 0 && threadIdx.x < NC) {
    int c = threadIdx.x >> 4, f = threadIdx.x & 15;
    size_t o = (size_t)c * (N + 1) * 16 + (size_t)N * 16 + f;
    propA[o] = 0.0f;
    propB[o] = 0.0f;
  }
  if (i < N) {
    int e = rowptr[i] + indeg[i];
    int end = rowptr[i + 1];
    for (; e < end; ++e) csr[e] = N;
  }
}

// ---------------------------------------------------------------------------
// Gather step, feature-chunked: chunk = blockIdx&3 so (under bid%8 XCD
// round-robin) each chunk's 3.2MB region stays resident in 2 XCDs' L2.
// 16-lane subgroup per node, lane = feature-in-chunk; csr via nontemporal
// loads (pure stream -- don't evict the hot chunk). Same 8-accumulator
// order as before -> bitwise-identical prop values.
__global__ __launch_bounds__(256) void gather_kernel(
    const float* __restrict__ cur, float* __restrict__ nxt,
    const int* __restrict__ csr, const int* __restrict__ rowptr,
    const float* __restrict__ dis, int N) {
  int chunk = blockIdx.x & 3;
  int nb = blockIdx.x >> 2;
  int sg = threadIdx.x >> 4;       // subgroup 0..15 -> node
  int lf = threadIdx.x & 15;       // feature within chunk
  int node = nb * 16 + sg;
  if (node >= N) return;
  const float* curC = cur + (size_t)chunk * (N + 1) * 16;
  float dc = dis[node];
  int beg = rowptr[node], end = rowptr[node + 1];
  size_t off = (size_t)node * 16 + lf;

  float a[8];
  a[0] = dc * dc * curC[off];      // self-loop: norm = dis[c]^2
#pragma unroll
  for (int u = 1; u < 8; ++u) a[u] = 0.0f;
  for (int i = beg; i < end; i += 8) {   // padded: full 8-batches
    int src[8];
#pragma unroll
    for (int u = 0; u < 8; ++u)
      src[u] = __builtin_nontemporal_load(&csr[i + u]);
    float ds[8];
#pragma unroll
    for (int u = 0; u < 8; ++u) ds[u] = dis[src[u]];
#pragma unroll
    for (int u = 0; u < 8; ++u)
      a[u] = fmaf(ds[u] * dc, curC[(size_t)src[u] * 16 + lf], a[u]);
  }
  float acc = ((a[0] + a[1]) + (a[2] + a[3])) + ((a[4] + a[5]) + (a[6] + a[7]));
  nxt[(size_t)chunk * (N + 1) * 16 + off] = acc;
}

// ---------------------------------------------------------------------------
// State/halting step: wave per node, lane = feature (chunk = lane>>4).
// Same shfl-tree z and state math as previous rounds -> bitwise identical.
template<bool FIRST, bool LAST>
__global__ __launch_bounds__(256) void state_kernel(
    const float* __restrict__ cur, const float* __restrict__ nxt,
    const float* __restrict__ hw, const float* __restrict__ hb,
    float* __restrict__ steps, float* __restrict__ sumh,
    int* __restrict__ cont, float* __restrict__ xacc,
    float* __restrict__ out0, float* __restrict__ out1,
    float* __restrict__ out2, int N) {
  int wid = (int)((blockIdx.x * blockDim.x + threadIdx.x) >> 6);
  if (wid >= N) return;
  int lane = threadIdx.x & 63;
  size_t choff = (size_t)(lane >> 4) * (N + 1) * 16 + (lane & 15);
  size_t nodeoff = (size_t)wid * 16;

  float acc  = nxt[choff + nodeoff];
  float oldv = cur[choff + nodeoff];

  // hh = sigmoid(acc . halt_w + halt_b)
  float z = acc * hw[lane];
#pragma unroll
  for (int off = 32; off > 0; off >>= 1) z += __shfl_xor(z, off);
  z += hb[0];
  float hh = 1.0f / (1.0f + expf(-z));

  float st, sh; int ct;
  if (FIRST) { st = 1.0f; sh = 0.0f; ct = 1; }
  else { st = steps[wid]; sh = sumh[wid]; ct = cont[wid]; }
  bool prob = ((sh + hh) < 0.99f) && (ct != 0);
  float pf = prob ? 1.0f : 0.0f;
  st += pf;
  sh += pf * hh;
  bool cond = prob && (st < (float)NITER);
  float pp = cond ? sh : (1.0f - sh);
  size_t rowoff = (size_t)wid * NC + lane;   // xacc/out0: standard layout

  if (!LAST) {
    if (ct != 0) {   // halted nodes: xacc/state frozen -> skip RMW
      float xa = FIRST ? 0.0f : xacc[rowoff];
      xacc[rowoff] = xa + (acc * pp + oldv * (1.0f - pp));
      if (lane == 0) { steps[wid] = st; sumh[wid] = sh; cont[wid] = prob ? 1 : 0; }
    }
  } else {
    float xa = xacc[rowoff];
    float xnew = (ct != 0) ? xa + (acc * pp + oldv * (1.0f - pp)) : xa;
    float v = xnew / st;
    float m = v;
#pragma unroll
    for (int off = 32; off > 0; off >>= 1) m = fmaxf(m, __shfl_xor(m, off));
    float e = expf(v - m);
    float s = e;
#pragma unroll
    for (int off = 32; off > 0; off >>= 1) s += __shfl_xor(s, off);
    __builtin_nontemporal_store(v - m - logf(s), &out0[rowoff]);
    if (lane == 0) {
      __builtin_nontemporal_store(st, &out1[wid]);
      __builtin_nontemporal_store(1.0f - sh, &out2[wid]);
    }
  }
}

// ---------------------------------------------------------------------------
extern "C" void kernel_launch(void* const* d_in, const int* in_sizes, int n_in,
                              void* d_out, int out_size, void* d_ws, size_t ws_size,
                              hipStream_t stream) {
  const float* x      = (const float*)d_in[0];
  const int*   ei     = (const int*)d_in[1];
  const float* W1     = (const float*)d_in[2];
  const float* b1     = (const float*)d_in[3];
  const float* W2     = (const float*)d_in[4];
  const float* b2     = (const float*)d_in[5];
  const float* halt_w = (const float*)d_in[6];
  const float* halt_b = (const float*)d_in[7];

  const int N = in_sizes[0] / F_IN;   // 50000
  const int E = in_sizes[1] / 2;      // 800000
  const int EP = E + 8 * N;           // padded-CSR capacity

  // workspace carve-up (256B aligned)
  char* p = (char*)d_ws;
  auto alloc = [&](size_t bytes) {
    void* r = (void*)p;
    p += (bytes + 255) & ~(size_t)255;
    return r;
  };
  float* propA  = (float*)alloc((size_t)(N + 1) * NC * 4);  // chunked layout
  float* propB  = (float*)alloc((size_t)(N + 1) * NC * 4);
  float* xacc   = (float*)alloc((size_t)N * NC * 4);
  int*   csr    = (int*)alloc((size_t)EP * 4);
  int*   rowptr = (int*)alloc((size_t)(N + 1) * 4);
  int*   deg_i  = (int*)alloc((size_t)N * 4);
  int*   indeg  = (int*)alloc((size_t)N * 4);
  int*   cursor = (int*)alloc((size_t)N * 4);
  float* dis    = (float*)alloc((size_t)(N + 1) * 4);       // +1 sentinel
  float* steps  = (float*)alloc((size_t)N * 4);
  float* sumh   = (float*)alloc((size_t)N * 4);
  int*   cont   = (int*)alloc((size_t)N * 4);
  int*   bsum   = (int*)alloc(1024);

  hipMemsetAsync(deg_i,  0, (size_t)N * 4, stream);
  hipMemsetAsync(indeg,  0, (size_t)N * 4, stream);
  hipMemsetAsync(cursor, 0, (size_t)N * 4, stream);

  const int nbN = (N + 255) / 256;   // 196
  const int nbE = (E + 255) / 256;   // 3125
  const int nbM = (N + BM - 1) / BM; // 391
  const int nbG = ((N + 15) / 16) * 4; // gather grid: 4 chunks x 3125

  mlp_kernel<<<nbM, 256, 0, stream>>>(x, W1, b1, W2, b2, propA, N);
  hist_kernel<<<nbE, 256, 0, stream>>>(ei, deg_i, indeg, E);
  scan_sum_kernel<<<nbN, 256, 0, stream>>>(indeg, bsum, deg_i, dis, N);
  scan_bsum_kernel<<<1, 256, 0, stream>>>(bsum, nbN);
  scan_final_kernel<<<nbN, 256, 0, stream>>>(indeg, bsum, rowptr, N);
  scatter_kernel<<<nbE, 256, 0, stream>>>(ei, rowptr, cursor, csr, E);
  pad_fill_kernel<<<nbN, 256, 0, stream>>>(rowptr, indeg, csr, propA, propB, N);

  float* out0 = (float*)d_out;
  float* out1 = out0 + (size_t)N * NC;
  float* out2 = out1 + N;

  const int nbW = (N + 3) / 4;       // 4 waves (nodes) per 256-thread block
  const float* cur = propA;
  float* nxt = propB;
  for (int it = 0; it < NITER; ++it) {
    gather_kernel<<<nbG, 256, 0, stream>>>(cur, nxt, csr, rowptr, dis, N);
    if (it == 0)
      state_kernel<true, false><<<nbW, 256, 0, stream>>>(
          cur, nxt, halt_w, halt_b, steps, sumh, cont, xacc, out0, out1, out2, N);
    else if (it == NITER - 1)
      state_kernel<false, true><<<nbW, 256, 0, stream>>>(
          cur, nxt, halt_w, halt_b, steps, sumh, cont, xacc, out0, out1, out2, N);
    else
      state_kernel<false, false><<<nbW, 256, 0, stream>>>(
          cur, nxt, halt_w, halt_b, steps, sumh, cont, xacc, out0, out1, out2, N);
    const float* t = nxt; nxt = (float*)cur; cur = t;
  }
}

// Round 13
// 545.670 us; speedup vs baseline: 1.6067x; 1.6067x over previous
//
#include <hip/hip_runtime.h>
#include <hip/hip_bf16.h>

#define F_IN 512
#define NC 64      // HID == N_CLS == 64
#define NITER 10
#define BM 128     // MLP tile rows (391 blocks)

typedef float fvec4 __attribute__((ext_vector_type(4)));  // clang-native vec

// ---------------------------------------------------------------------------
// Fused tiled MLP: out[r,:] = relu(x[r,:] @ W1 + b1) @ W2 + b2   (all fp32)
// R10 structure: 256 threads, tile 128x64, 8x4 per thread; xs row-major
// [row][16 chunks], chunk kc at kc ^ ((row>>3)&7) (SQ_LDS_BANK_CONFLICT = 0,
// verified R9/R10). ~82us = ~1.5x LDS floor; all alternative shapes regressed
// (R6 grid-starve, R7 occupancy, R11 T14 reg-spill). Parked at this config.
__global__ __launch_bounds__(256) void mlp_kernel(
    const float* __restrict__ x, const float* __restrict__ W1,
    const float* __restrict__ b1, const float* __restrict__ W2,
    const float* __restrict__ b2, float* __restrict__ out, int N) {
  __shared__ float xs[BM * NC];    // 32KB x k-tile / later h
  __shared__ float ws[NC * NC];    // 16KB W1 k-tile / later W2
  const int tid  = threadIdx.x;
  const int brow = blockIdx.x * BM;
  const int rg = tid >> 4;         // 0..15 row-group (8 rows each)
  const int cg = tid & 15;         // 0..15 col-group (4 cols each)
  const int r0 = rg * 8;
  const int c0 = cg * 4;
  const int keyr = rg & 7;

  float acc[8][4];
#pragma unroll
  for (int j = 0; j < 4; ++j) {
    float bv = b1[c0 + j];
#pragma unroll
    for (int i = 0; i < 8; ++i) acc[i][j] = bv;
  }

  for (int kt = 0; kt < F_IN; kt += 64) {
#pragma unroll
    for (int q = 0; q < 8; ++q) {
      int c = q * 256 + tid;           // 2048 chunks
      int row = c >> 4, kc = c & 15;
      int gr = brow + row; if (gr >= N) gr = N - 1;
      float4 v = *reinterpret_cast<const float4*>(&x[(size_t)gr * F_IN + kt + kc * 4]);
      *reinterpret_cast<float4*>(&xs[row * NC + ((kc ^ ((row >> 3) & 7)) << 2)]) = v;
    }
#pragma unroll
    for (int q = 0; q < 4; ++q) {
      int c = q * 256 + tid;           // 1024 chunks
      *reinterpret_cast<float4*>(&ws[c * 4]) =
          *reinterpret_cast<const float4*>(&W1[(size_t)kt * NC + c * 4]);
    }
    __syncthreads();
#pragma unroll 4
    for (int kc = 0; kc < 16; ++kc) {
      float4 xq[8];
#pragma unroll
      for (int i = 0; i < 8; ++i)
        xq[i] = *reinterpret_cast<const float4*>(&xs[(r0 + i) * NC + ((kc ^ keyr) << 2)]);
#pragma unroll
      for (int m = 0; m < 4; ++m) {
        float4 wv = *reinterpret_cast<const float4*>(&ws[(kc * 4 + m) * NC + c0]);
        float wr[4] = {wv.x, wv.y, wv.z, wv.w};
#pragma unroll
        for (int i = 0; i < 8; ++i) {
          float xm = reinterpret_cast<const float*>(&xq[i])[m];
#pragma unroll
          for (int j = 0; j < 4; ++j) acc[i][j] = fmaf(xm, wr[j], acc[i][j]);
        }
      }
    }
    __syncthreads();
  }

  // ReLU; h -> xs (same swizzled layout; thread's 4 cols == chunk cg)
#pragma unroll
  for (int i = 0; i < 8; ++i) {
    float4 hv = make_float4(fmaxf(acc[i][0], 0.f), fmaxf(acc[i][1], 0.f),
                            fmaxf(acc[i][2], 0.f), fmaxf(acc[i][3], 0.f));
    *reinterpret_cast<float4*>(&xs[(r0 + i) * NC + ((cg ^ keyr) << 2)]) = hv;
  }
#pragma unroll
  for (int q = 0; q < 4; ++q) {
    int c = q * 256 + tid;
    *reinterpret_cast<float4*>(&ws[c * 4]) =
        *reinterpret_cast<const float4*>(&W2[c * 4]);
  }
  float acc2[8][4];
#pragma unroll
  for (int j = 0; j < 4; ++j) {
    float bv = b2[c0 + j];
#pragma unroll
    for (int i = 0; i < 8; ++i) acc2[i][j] = bv;
  }
  __syncthreads();
#pragma unroll 4
  for (int kc = 0; kc < 16; ++kc) {
    float4 xq[8];
#pragma unroll
    for (int i = 0; i < 8; ++i)
      xq[i] = *reinterpret_cast<const float4*>(&xs[(r0 + i) * NC + ((kc ^ keyr) << 2)]);
#pragma unroll
    for (int m = 0; m < 4; ++m) {
      float4 wv = *reinterpret_cast<const float4*>(&ws[(kc * 4 + m) * NC + c0]);
      float wr[4] = {wv.x, wv.y, wv.z, wv.w};
#pragma unroll
      for (int i = 0; i < 8; ++i) {
        float xm = reinterpret_cast<const float*>(&xq[i])[m];
#pragma unroll
        for (int j = 0; j < 4; ++j) acc2[i][j] = fmaf(xm, wr[j], acc2[i][j]);
      }
    }
  }
#pragma unroll
  for (int i = 0; i < 8; ++i) {
    int gr = brow + r0 + i;
    if (gr < N) {
      fvec4 o = {acc2[i][0], acc2[i][1], acc2[i][2], acc2[i][3]};
      __builtin_nontemporal_store(o, reinterpret_cast<fvec4*>(&out[(size_t)gr * NC + c0]));
    }
  }
}

// ---------------------------------------------------------------------------
// Degree histograms (int atomics -> deterministic counts).
__global__ __launch_bounds__(256) void hist_kernel(
    const int* __restrict__ ei, int* __restrict__ deg_i,
    int* __restrict__ indeg, int E) {
  int e = blockIdx.x * blockDim.x + threadIdx.x;
  if (e < E) {
    atomicAdd(&deg_i[ei[e]], 1);       // row = edge_index[0]
    atomicAdd(&indeg[ei[E + e]], 1);   // col = edge_index[1]
  }
}

// ---------------------------------------------------------------------------
// Exclusive scan of PADDED indeg (multiple of 8) -> rowptr; also dis[].
// dis has N+1 entries: dis[N] = 0 is the pad-sentinel weight.
__device__ __forceinline__ int pad8(int v) { return (v + 7) & ~7; }

__global__ __launch_bounds__(256) void scan_sum_kernel(
    const int* __restrict__ indeg, int* __restrict__ bsum,
    const int* __restrict__ deg_i, float* __restrict__ dis, int N) {
  __shared__ int sm[256];
  int tid = threadIdx.x;
  int i = blockIdx.x * 256 + tid;
  sm[tid] = (i < N) ? pad8(indeg[i]) : 0;
  if (i < N) dis[i] = 1.0f / sqrtf((float)(deg_i[i] + 1));  // +1 self-loop
  if (i == N) dis[N] = 0.0f;   // sentinel: pad edges have zero weight
  __syncthreads();
  for (int s = 128; s > 0; s >>= 1) {
    if (tid < s) sm[tid] += sm[tid + s];
    __syncthreads();
  }
  if (tid == 0) bsum[blockIdx.x] = sm[0];
}

__global__ __launch_bounds__(256) void scan_bsum_kernel(int* __restrict__ bsum, int nb) {
  __shared__ int sm[256];
  int tid = threadIdx.x;
  int v = (tid < nb) ? bsum[tid] : 0;
  sm[tid] = v;
  __syncthreads();
  for (int s = 1; s < 256; s <<= 1) {
    int t = (tid >= s) ? sm[tid - s] : 0;
    __syncthreads();
    sm[tid] += t;
    __syncthreads();
  }
  if (tid < nb) bsum[tid] = sm[tid] - v;  // exclusive
}

__global__ __launch_bounds__(256) void scan_final_kernel(
    const int* __restrict__ indeg, const int* __restrict__ bsum,
    int* __restrict__ rowptr, int N) {
  __shared__ int sm[256];
  int tid = threadIdx.x;
  int i = blockIdx.x * 256 + tid;
  int v = (i < N) ? pad8(indeg[i]) : 0;
  sm[tid] = v;
  __syncthreads();
  for (int s = 1; s < 256; s <<= 1) {
    int t = (tid >= s) ? sm[tid - s] : 0;
    __syncthreads();
    sm[tid] += t;
    __syncthreads();
  }
  if (i < N) {
    rowptr[i] = bsum[blockIdx.x] + sm[tid] - v;
    if (i == N - 1) rowptr[N] = bsum[blockIdx.x] + sm[tid];  // padded total
  }
}

// ---------------------------------------------------------------------------
// Build destination-CSR: csr[pos] = src only (4B). Weight is recomputed
// per-iteration as dis[src]*dis[c] (identical operands -> identical bits).
__global__ __launch_bounds__(256) void scatter_kernel(
    const int* __restrict__ ei, const int* __restrict__ rowptr,
    int* __restrict__ cursor, int* __restrict__ csr, int E) {
  int e = blockIdx.x * blockDim.x + threadIdx.x;
  if (e < E) {
    int s = ei[e];
    int c = ei[E + e];
    int pos = rowptr[c] + atomicAdd(&cursor[c], 1);
    csr[pos] = s;
  }
}

// Fill pad slots with sentinel src=N (dis[N]=0 -> zero-weight no-op edge);
// also zero prop row N so the pad gather reads defined memory.
__global__ __launch_bounds__(256) void pad_fill_kernel(
    const int* __restrict__ rowptr, const int* __restrict__ indeg,
    int* __restrict__ csr, float* __restrict__ propA,
    float* __restrict__ propB, int N) {
  int i = blockIdx.x * blockDim.x + threadIdx.x;
  if (blockIdx.x == 0 && threadIdx.x < NC) {
    propA[(size_t)N * NC + threadIdx.x] = 0.0f;
    propB[(size_t)N * NC + threadIdx.x] = 0.0f;
  }
  if (i < N) {
    int e = rowptr[i] + indeg[i];
    int end = rowptr[i + 1];
    for (; e < end; ++e) csr[e] = N;
  }
}

// ---------------------------------------------------------------------------
// One adaptive-propagation step. One wave per node, lane = feature.
// csr entry = 4B src; weight = dis[src]*dc recomputed (dis is 200KB,
// L1/L2-resident). FIRST inlines initial state; LAST fuses log_softmax.
// Per-iter traffic ~240MB at ~6TB/s effective -- at the fabric ceiling
// (pad8/nt/predication/chunking probes all null or negative, R7-R12).
template<bool FIRST, bool LAST>
__global__ __launch_bounds__(256) void prop_step_kernel(
    const float* __restrict__ prop, float* __restrict__ prop_new,
    const int* __restrict__ csr, const int* __restrict__ rowptr,
    const float* __restrict__ dis, const float* __restrict__ hw,
    const float* __restrict__ hb, float* __restrict__ steps,
    float* __restrict__ sumh, int* __restrict__ cont,
    float* __restrict__ xacc, float* __restrict__ out0,
    float* __restrict__ out1, float* __restrict__ out2, int N) {
  int wid = (int)((blockIdx.x * blockDim.x + threadIdx.x) >> 6);
  if (wid >= N) return;
  int lane = threadIdx.x & 63;
  size_t rowoff = (size_t)wid * NC + lane;

  float oldv = prop[rowoff];
  float dc = dis[wid];
  int beg = __builtin_amdgcn_readfirstlane(rowptr[wid]);
  int end = __builtin_amdgcn_readfirstlane(rowptr[wid + 1]);

  float a[8];
  a[0] = dc * dc * oldv;   // self-loop: norm = dis[c]^2
#pragma unroll
  for (int u = 1; u < 8; ++u) a[u] = 0.0f;
  for (int i = beg; i < end; i += 8) {   // padded: always full 8-batches
    int src[8];
#pragma unroll
    for (int u = 0; u < 8; ++u) src[u] = csr[i + u];
    float dsrc[8];
#pragma unroll
    for (int u = 0; u < 8; ++u) dsrc[u] = dis[src[u]];
#pragma unroll
    for (int u = 0; u < 8; ++u)
      a[u] = fmaf(dsrc[u] * dc, prop[(size_t)src[u] * NC + lane], a[u]);
  }
  float acc = ((a[0] + a[1]) + (a[2] + a[3])) + ((a[4] + a[5]) + (a[6] + a[7]));
  if (!LAST) prop_new[rowoff] = acc;

  // hh = sigmoid(acc . halt_w + halt_b)
  float z = acc * hw[lane];
#pragma unroll
  for (int off = 32; off > 0; off >>= 1) z += __shfl_xor(z, off);
  z += hb[0];
  float hh = 1.0f / (1.0f + expf(-z));

  float st, sh; int ct;
  if (FIRST) { st = 1.0f; sh = 0.0f; ct = 1; }
  else { st = steps[wid]; sh = sumh[wid]; ct = cont[wid]; }
  bool prob = ((sh + hh) < 0.99f) && (ct != 0);
  float pf = prob ? 1.0f : 0.0f;
  st += pf;
  sh += pf * hh;
  bool cond = prob && (st < (float)NITER);
  float pp = cond ? sh : (1.0f - sh);

  if (!LAST) {
    if (ct != 0) {   // halted nodes: xacc/state frozen -> skip RMW
      float xa = FIRST ? 0.0f : xacc[rowoff];
      xacc[rowoff] = xa + (acc * pp + oldv * (1.0f - pp));
      if (lane == 0) { steps[wid] = st; sumh[wid] = sh; cont[wid] = prob ? 1 : 0; }
    }
  } else {
    // fused final: out0 = log_softmax(xacc/steps), out1 = steps, out2 = 1-sumh
    float xa = xacc[rowoff];
    float xnew = (ct != 0) ? xa + (acc * pp + oldv * (1.0f - pp)) : xa;
    float v = xnew / st;
    float m = v;
#pragma unroll
    for (int off = 32; off > 0; off >>= 1) m = fmaxf(m, __shfl_xor(m, off));
    float e = expf(v - m);
    float s = e;
#pragma unroll
    for (int off = 32; off > 0; off >>= 1) s += __shfl_xor(s, off);
    __builtin_nontemporal_store(v - m - logf(s), &out0[rowoff]);
    if (lane == 0) {
      __builtin_nontemporal_store(st, &out1[wid]);
      __builtin_nontemporal_store(1.0f - sh, &out2[wid]);
    }
  }
}

// ---------------------------------------------------------------------------
extern "C" void kernel_launch(void* const* d_in, const int* in_sizes, int n_in,
                              void* d_out, int out_size, void* d_ws, size_t ws_size,
                              hipStream_t stream) {
  const float* x      = (const float*)d_in[0];
  const int*   ei     = (const int*)d_in[1];
  const float* W1     = (const float*)d_in[2];
  const float* b1     = (const float*)d_in[3];
  const float* W2     = (const float*)d_in[4];
  const float* b2     = (const float*)d_in[5];
  const float* halt_w = (const float*)d_in[6];
  const float* halt_b = (const float*)d_in[7];

  const int N = in_sizes[0] / F_IN;   // 50000
  const int E = in_sizes[1] / 2;      // 800000
  const int EP = E + 8 * N;           // padded-CSR capacity

  // workspace carve-up (256B aligned)
  char* p = (char*)d_ws;
  auto alloc = [&](size_t bytes) {
    void* r = (void*)p;
    p += (bytes + 255) & ~(size_t)255;
    return r;
  };
  float* propA  = (float*)alloc((size_t)(N + 1) * NC * 4);  // +1 sentinel row
  float* propB  = (float*)alloc((size_t)(N + 1) * NC * 4);
  float* xacc   = (float*)alloc((size_t)N * NC * 4);
  int*   csr    = (int*)alloc((size_t)EP * 4);
  int*   rowptr = (int*)alloc((size_t)(N + 1) * 4);
  int*   deg_i  = (int*)alloc((size_t)N * 4);
  int*   indeg  = (int*)alloc((size_t)N * 4);
  int*   cursor = (int*)alloc((size_t)N * 4);
  float* dis    = (float*)alloc((size_t)(N + 1) * 4);       // +1 sentinel
  float* steps  = (float*)alloc((size_t)N * 4);
  float* sumh   = (float*)alloc((size_t)N * 4);
  int*   cont   = (int*)alloc((size_t)N * 4);
  int*   bsum   = (int*)alloc(1024);

  hipMemsetAsync(deg_i,  0, (size_t)N * 4, stream);
  hipMemsetAsync(indeg,  0, (size_t)N * 4, stream);
  hipMemsetAsync(cursor, 0, (size_t)N * 4, stream);

  const int nbN = (N + 255) / 256;   // 196
  const int nbE = (E + 255) / 256;   // 3125
  const int nbM = (N + BM - 1) / BM; // 391

  mlp_kernel<<<nbM, 256, 0, stream>>>(x, W1, b1, W2, b2, propA, N);
  hist_kernel<<<nbE, 256, 0, stream>>>(ei, deg_i, indeg, E);
  scan_sum_kernel<<<nbN, 256, 0, stream>>>(indeg, bsum, deg_i, dis, N);
  scan_bsum_kernel<<<1, 256, 0, stream>>>(bsum, nbN);
  scan_final_kernel<<<nbN, 256, 0, stream>>>(indeg, bsum, rowptr, N);
  scatter_kernel<<<nbE, 256, 0, stream>>>(ei, rowptr, cursor, csr, E);
  pad_fill_kernel<<<nbN, 256, 0, stream>>>(rowptr, indeg, csr, propA, propB, N);

  float* out0 = (float*)d_out;
  float* out1 = out0 + (size_t)N * NC;
  float* out2 = out1 + N;

  const int nbW = (N + 3) / 4;       // 4 waves (nodes) per 256-thread block
  const float* cur = propA;
  float* nxt = propB;
  prop_step_kernel<true, false><<<nbW, 256, 0, stream>>>(
      cur, nxt, csr, rowptr, dis, halt_w, halt_b, steps, sumh, cont, xacc,
      out0, out1, out2, N);
  { const float* t = nxt; nxt = (float*)cur; cur = t; }
  for (int it = 1; it < NITER - 1; ++it) {
    prop_step_kernel<false, false><<<nbW, 256, 0, stream>>>(
        cur, nxt, csr, rowptr, dis, halt_w, halt_b, steps, sumh, cont, xacc,
        out0, out1, out2, N);
    const float* t = nxt; nxt = (float*)cur; cur = t;
  }
  prop_step_kernel<false, true><<<nbW, 256, 0, stream>>>(
      cur, nxt, csr, rowptr, dis, halt_w, halt_b, steps, sumh, cont, xacc,
      out0, out1, out2, N);
}